// Round 14
// baseline (199.497 us; speedup 1.0000x reference)
//
#include <hip/hip_runtime.h>
#include <hip/hip_fp16.h>

#define IN_SIZE 256
#define HIDDEN 16
#define OUT_SIZE 64
#define BSHIFT 8            // bucket = row >> 8 (256 rows)
#define BROWS 256
#define NBUCK 512           // supports n <= 131072
#define EB 8192             // edges per bin block
#define BINBLK 1024
#define EPT 8
#define NBLK_MAX 512        // supports nedges <= 4.19M
#define WSTR 20
#define CAP 8704            // LDS-resident records per 256-row bucket (69.6KB)
#define KPT 17              // CAP/512 records per thread (register-staged)

// ---------------- fallback-path kernels ----------------
__global__ __launch_bounds__(256) void zero_int_kernel(int* __restrict__ a, long n) {
    long i = (long)blockIdx.x * 256 + threadIdx.x;
    long stride = (long)gridDim.x * 256;
    for (; i < n; i += stride) a[i] = 0;
}

__global__ __launch_bounds__(256) void dense1_kernel(
    const float* __restrict__ X, const float* __restrict__ W1,
    const float* __restrict__ b1, float* __restrict__ H1, int n) {
    __shared__ float w[HIDDEN * IN_SIZE];
    for (int i = threadIdx.x; i < HIDDEN * IN_SIZE; i += 256) {
        int h = i >> 8;
        int k = i & 255;
        w[k * HIDDEN + h] = W1[i];
    }
    __syncthreads();
    int t = threadIdx.x;
    int node = blockIdx.x * 16 + (t >> 4);
    int h = t & 15;
    if (node >= n) return;
    const float4* xr = reinterpret_cast<const float4*>(X + (size_t)node * IN_SIZE);
    float acc = b1[h];
#pragma unroll 8
    for (int kk = 0; kk < IN_SIZE / 4; ++kk) {
        float4 x = xr[kk];
        const float* wr = &w[(kk * 4) * HIDDEN + h];
        acc += x.x * wr[0] + x.y * wr[HIDDEN] + x.z * wr[2 * HIDDEN] + x.w * wr[3 * HIDDEN];
    }
    H1[(size_t)node * HIDDEN + h] = acc;
}

__global__ __launch_bounds__(256) void spmm16_kernel(
    const int* __restrict__ row, const int* __restrict__ col,
    const float* __restrict__ val, const float* __restrict__ Hin,
    float* __restrict__ Sout, float* __restrict__ deg, long nedges, int relu_in) {
    long t = (long)blockIdx.x * 256 + threadIdx.x;
    long e = t >> 4;
    if (e >= nedges) return;
    int k = (int)(t & 15);
    int r = row[e];
    int c = col[e];
    float v = val[e];
    float x = Hin[(size_t)c * HIDDEN + k];
    if (relu_in) x = fmaxf(x, 0.0f);
    atomicAdd(&Sout[(size_t)r * HIDDEN + k], v * x);
    if (deg != nullptr && k == 0) atomicAdd(&deg[r], v);
}

__global__ __launch_bounds__(256) void dense2_kernel(
    const float* __restrict__ T, const float* __restrict__ deg,
    const float* __restrict__ W2, const float* __restrict__ b2,
    float* __restrict__ out, int n) {
    __shared__ float w[OUT_SIZE * HIDDEN];
    for (int i = threadIdx.x; i < OUT_SIZE * HIDDEN; i += 256) {
        int o = i / HIDDEN;
        int h = i % HIDDEN;
        w[h * OUT_SIZE + o] = W2[i];
    }
    __syncthreads();
    int node = blockIdx.x * 4 + (threadIdx.x >> 6);
    int o = threadIdx.x & 63;
    if (node >= n) return;
    float acc = deg[node] * b2[o];
#pragma unroll
    for (int h = 0; h < HIDDEN; ++h)
        acc += T[(size_t)node * HIDDEN + h] * w[h * OUT_SIZE + o];
    out[(size_t)node * OUT_SIZE + o] = fmaxf(acc, 0.0f);
}

// ---------------- prep: bin (blocks < nblk) + dense1 (rest) ----------------
// record: x = (lr<<24)|col ; y = val bits
// meta: lr<<24 | bb<<13 | slot  (lr<256, bb<512, slot<8192; bits22-23 = 0)
__global__ void prep_kernel(
    const int* __restrict__ row, const int* __restrict__ col,
    const float* __restrict__ val, uint2* __restrict__ bin,
    int* __restrict__ dirT, int nblk, long nedges,
    const float* __restrict__ X, const float* __restrict__ W1,
    const float* __restrict__ b1, __half2* __restrict__ H1, int n) {
    __shared__ union USh {
        struct { int hist[NBUCK]; int lbase[NBUCK]; int s[NBUCK];
                 unsigned int staged[EB * 2]; } b;          // 72 KB
        float w[IN_SIZE * WSTR];                            // 20 KB
    } u;
    int tid = threadIdx.x;
    if (blockIdx.x < nblk) {
        // ---------- bin part ----------
        int blk = blockIdx.x;
        long base = (long)blk * EB;
        int ecount = (int)(((nedges - base) < (long)EB) ? (nedges - base) : (long)EB);
        if (tid < NBUCK) u.b.hist[tid] = 0;
        __syncthreads();
        unsigned int meta[EPT], cc[EPT], vv[EPT];
        if (ecount == EB) {
            long e8 = base + (long)tid * EPT;
            int4 ra = *reinterpret_cast<const int4*>(row + e8);
            int4 rb = *reinterpret_cast<const int4*>(row + e8 + 4);
            int4 ca = *reinterpret_cast<const int4*>(col + e8);
            int4 cb = *reinterpret_cast<const int4*>(col + e8 + 4);
            float4 va = *reinterpret_cast<const float4*>(val + e8);
            float4 vb = *reinterpret_cast<const float4*>(val + e8 + 4);
            int rr[8] = {ra.x, ra.y, ra.z, ra.w, rb.x, rb.y, rb.z, rb.w};
            int cr[8] = {ca.x, ca.y, ca.z, ca.w, cb.x, cb.y, cb.z, cb.w};
            float vr[8] = {va.x, va.y, va.z, va.w, vb.x, vb.y, vb.z, vb.w};
#pragma unroll
            for (int i = 0; i < EPT; ++i) {
                int r = rr[i];
                int bb = r >> BSHIFT;
                int slot = atomicAdd(&u.b.hist[bb], 1);
                meta[i] = ((unsigned int)(r & (BROWS - 1)) << 24) |
                          ((unsigned int)bb << 13) | (unsigned int)slot;
                cc[i] = (unsigned int)cr[i];
                vv[i] = __float_as_uint(vr[i]);
            }
        } else {
#pragma unroll
            for (int i = 0; i < EPT; ++i) {
                int k = tid * EPT + i;
                meta[i] = 0xFFFFFFFFu;
                if (k < ecount) {
                    int r = row[base + k];
                    cc[i] = (unsigned int)col[base + k];
                    vv[i] = __float_as_uint(val[base + k]);
                    int bb = r >> BSHIFT;
                    int slot = atomicAdd(&u.b.hist[bb], 1);
                    meta[i] = ((unsigned int)(r & (BROWS - 1)) << 24) |
                              ((unsigned int)bb << 13) | (unsigned int)slot;
                }
            }
        }
        __syncthreads();
        if (tid < NBUCK) u.b.s[tid] = u.b.hist[tid];
        __syncthreads();
        for (int off = 1; off < NBUCK; off <<= 1) {
            int t = (tid >= off && tid < NBUCK) ? u.b.s[tid - off] : 0;
            __syncthreads();
            if (tid < NBUCK) u.b.s[tid] += t;
            __syncthreads();
        }
        if (tid < NBUCK) u.b.lbase[tid] = u.b.s[tid] - u.b.hist[tid];
        __syncthreads();
        if (tid <= NBUCK)
            dirT[(size_t)tid * nblk + blk] = (tid < NBUCK) ? u.b.lbase[tid] : ecount;
#pragma unroll
        for (int i = 0; i < EPT; ++i) {
            if (meta[i] != 0xFFFFFFFFu) {
                int bb = (int)((meta[i] >> 13) & 0x1FF);
                int p = u.b.lbase[bb] + (int)(meta[i] & 0x1FFF);
                u.b.staged[2 * p]     = (meta[i] & 0xFF000000u) | cc[i];
                u.b.staged[2 * p + 1] = vv[i];
            }
        }
        __syncthreads();
        for (int j = tid; j < ecount; j += BINBLK)
            bin[base + j] = make_uint2(u.b.staged[2 * j], u.b.staged[2 * j + 1]);
    } else {
        // ---------- dense1 part (256 nodes/block) ----------
        for (int i = tid; i < HIDDEN * IN_SIZE; i += BINBLK) {
            int h = i >> 8;
            int k = i & 255;
            u.w[k * WSTR + h] = W1[i];
        }
        __syncthreads();
        int node = (blockIdx.x - nblk) * 256 + (tid >> 2);
        int q = tid & 3;
        if (node >= n) return;
        float acc[16];
#pragma unroll
        for (int h = 0; h < 16; ++h) acc[h] = 0.f;
        const float4* xr = reinterpret_cast<const float4*>(X + (size_t)node * IN_SIZE);
#pragma unroll 8
        for (int kk = 0; kk < 16; ++kk) {
            float4 x = xr[q + 4 * kk];
            const float* wr = &u.w[(kk * 16 + q * 4) * WSTR];
#pragma unroll
            for (int j = 0; j < 4; ++j) {
                float xs = (j == 0) ? x.x : (j == 1) ? x.y : (j == 2) ? x.z : x.w;
                const float* wj = wr + j * WSTR;
#pragma unroll
                for (int h = 0; h < 16; ++h)
                    acc[h] += xs * wj[h];
            }
        }
#pragma unroll
        for (int h = 0; h < 16; ++h) {
            acc[h] += __shfl_xor(acc[h], 1, 4);
            acc[h] += __shfl_xor(acc[h], 2, 4);
        }
        const float4 bb = reinterpret_cast<const float4*>(b1)[q];
        int hb = q * 4;
        __half2 o0 = __floats2half2_rn(acc[hb] + bb.x, acc[hb + 1] + bb.y);
        __half2 o1 = __floats2half2_rn(acc[hb + 2] + bb.z, acc[hb + 3] + bb.w);
        uint2 pk;
        pk.x = *reinterpret_cast<unsigned int*>(&o0);
        pk.y = *reinterpret_cast<unsigned int*>(&o1);
        reinterpret_cast<uint2*>(H1)[(size_t)node * 4 + q] = pk;
    }
}

// ---------------- shared helpers ----------------
__device__ __forceinline__ int bsearch_pfx(const int* pfx, int p) {
    int lo = 0;
#pragma unroll
    for (int sh = 8; sh >= 0; --sh) {
        int mid = lo + (1 << sh);
        if (mid < NBLK_MAX && pfx[mid] <= p) lo = mid;
    }
    return lo;
}

__device__ __forceinline__ void fma_h(float4& a, uint2 h, float v) {
    __half2 lo = *reinterpret_cast<const __half2*>(&h.x);
    __half2 hi = *reinterpret_cast<const __half2*>(&h.y);
    float2 f0 = __half22float2(lo), f1 = __half22float2(hi);
    a.x += v * f0.x; a.y += v * f0.y; a.z += v * f1.x; a.w += v * f1.y;
}

__device__ __forceinline__ void grid_sync(unsigned int* bar, unsigned int nblocks) {
    __syncthreads();
    if (threadIdx.x == 0) {
        __threadfence();                     // release Ah writes device-wide
        unsigned int v = atomicAdd(&bar[0], 1u);
        if (v == nblocks - 1u) {
            atomicExch(&bar[1], 1u);
        } else {
            while (atomicAdd(&bar[1], 0u) == 0u) { __builtin_amdgcn_s_sleep(8); }
        }
        __threadfence();                     // acquire
    }
    __syncthreads();
}

// ---------------- fused: sort + spmm1 | grid barrier | spmm2 + dense2 ------
// 512 thr / 256-row bucket; LDS ~78KB -> 2 blocks/CU -> capacity 512 >= grid.
__global__ __launch_bounds__(512, 4) void spmm_fused_kernel(
    const uint2* __restrict__ bin, const int* __restrict__ dirT,
    const uint2* __restrict__ H1h, __half2* __restrict__ Ah,
    const float* __restrict__ W2, const float* __restrict__ b2,
    float* __restrict__ out, unsigned int* __restrict__ bar,
    int n, int nblk) {
    __shared__ union FSh {
        struct { int gs[NBLK_MAX]; int pfx[NBLK_MAX]; unsigned short rl[NBLK_MAX]; } p1;
        struct { float w2[HIDDEN * OUT_SIZE]; float b2s[OUT_SIZE]; } p2;
    } u;
    __shared__ int s[NBLK_MAX];
    __shared__ int cnt[BROWS], sbase[BROWS];
    __shared__ float dacc[BROWS];
    __shared__ int mTot;
    __shared__ uint2 eld[CAP];
    int d = blockIdx.x, tid = threadIdx.x, q = tid & 3;
    if (tid < nblk) {
        int a = dirT[(size_t)d * nblk + tid];
        int b = dirT[(size_t)(d + 1) * nblk + tid];
        u.p1.gs[tid] = tid * EB + a;
        u.p1.rl[tid] = (unsigned short)(b - a);
    } else {
        u.p1.gs[tid] = 0;
        u.p1.rl[tid] = 0;
    }
    __syncthreads();
    int x = (int)u.p1.rl[tid];
    s[tid] = x;
    __syncthreads();
    for (int off = 1; off < NBLK_MAX; off <<= 1) {
        int t = (tid >= off) ? s[tid - off] : 0;
        __syncthreads();
        s[tid] += t;
        __syncthreads();
    }
    u.p1.pfx[tid] = s[tid] - x;
    if (tid == NBLK_MAX - 1) mTot = s[tid];
    if (tid < BROWS) { cnt[tid] = 0; dacc[tid] = 0.f; }
    __syncthreads();
    int m = mTot;
    bool fits = (m <= CAP);
    float* accf = (float*)eld;
    if (fits) {
        uint2 regs[KPT];
        unsigned int sl[KPT];    // lr<<16 | slot
#pragma unroll
        for (int k = 0; k < KPT; ++k) {
            int p = tid + (k << 9);
            if (p < m) {
                int blk = bsearch_pfx(u.p1.pfx, p);
                uint2 rec = bin[(size_t)u.p1.gs[blk] + (p - u.p1.pfx[blk])];
                int lr = rec.x >> 24;
                regs[k] = make_uint2(rec.x & 0xFFFFFF, rec.y);
                sl[k] = ((unsigned int)lr << 16) |
                        (unsigned int)atomicAdd(&cnt[lr], 1);
            }
        }
        __syncthreads();
        int cx = (tid < BROWS) ? cnt[tid] : 0;
        if (tid < BROWS) s[tid] = cx;
        __syncthreads();
        for (int off = 1; off < BROWS; off <<= 1) {
            int t = (tid >= off && tid < BROWS) ? s[tid - off] : 0;
            __syncthreads();
            if (tid < BROWS) s[tid] += t;
            __syncthreads();
        }
        if (tid < BROWS) sbase[tid] = s[tid] - cx;
        __syncthreads();
#pragma unroll
        for (int k = 0; k < KPT; ++k) {
            int p = tid + (k << 9);
            if (p < m) eld[sbase[sl[k] >> 16] + (sl[k] & 0xFFFF)] = regs[k];
        }
        __syncthreads();
        // p1 dead -> stage W2/b2 for phase-2 epilogue
        for (int i = tid; i < HIDDEN * OUT_SIZE; i += 512)
            u.p2.w2[(i & 15) * OUT_SIZE + (i >> 4)] = W2[i];
        if (tid < OUT_SIZE) u.p2.b2s[tid] = b2[tid];
    } else {
        for (int i = tid; i < BROWS * 17; i += 512) accf[i] = 0.f;
        __syncthreads();
        for (int p = tid; p < m; p += 512) {
            int blk = bsearch_pfx(u.p1.pfx, p);
            uint2 rec = bin[(size_t)u.p1.gs[blk] + (p - u.p1.pfx[blk])];
            int lr = rec.x >> 24;
            int c = rec.x & 0xFFFFFF;
            float v = __uint_as_float(rec.y);
            const __half2* hp = reinterpret_cast<const __half2*>(H1h + (size_t)c * 4);
#pragma unroll
            for (int j = 0; j < 8; ++j) {
                float2 f = __half22float2(hp[j]);
                atomicAdd(&accf[lr * 17 + 2 * j], v * f.x);
                atomicAdd(&accf[lr * 17 + 2 * j + 1], v * f.y);
            }
            atomicAdd(&dacc[lr], v);
        }
        __syncthreads();
    }
    auto row_pull = [&](int lr, const uint2* __restrict__ Hsrc,
                        float4& aout, float& dgout) {
        float4 a0 = {0,0,0,0}, a1 = {0,0,0,0}, a2 = {0,0,0,0}, a3 = {0,0,0,0};
        float dg = 0.f;
        int e = sbase[lr], e1 = e + cnt[lr];
        for (; e + 4 <= e1; e += 4) {
            uint2 r0 = eld[e], r1 = eld[e + 1], r2 = eld[e + 2], r3 = eld[e + 3];
            uint2 h0 = Hsrc[(size_t)r0.x * 4 + q];
            uint2 h1 = Hsrc[(size_t)r1.x * 4 + q];
            uint2 h2 = Hsrc[(size_t)r2.x * 4 + q];
            uint2 h3 = Hsrc[(size_t)r3.x * 4 + q];
            float v0 = __uint_as_float(r0.y), v1 = __uint_as_float(r1.y);
            float v2 = __uint_as_float(r2.y), v3 = __uint_as_float(r3.y);
            fma_h(a0, h0, v0); fma_h(a1, h1, v1);
            fma_h(a2, h2, v2); fma_h(a3, h3, v3);
            dg += v0 + v1 + v2 + v3;
        }
        for (; e < e1; ++e) {
            uint2 rr = eld[e];
            uint2 h = Hsrc[(size_t)rr.x * 4 + q];
            float v = __uint_as_float(rr.y);
            fma_h(a0, h, v);
            dg += v;
        }
        a0.x += a1.x + a2.x + a3.x;
        a0.y += a1.y + a2.y + a3.y;
        a0.z += a1.z + a2.z + a3.z;
        a0.w += a1.w + a2.w + a3.w;
        aout = a0; dgout = dg;
    };
    auto ld_accf = [&](int lr) {
        float4 a;
        a.x = accf[lr * 17 + 4 * q];
        a.y = accf[lr * 17 + 4 * q + 1];
        a.z = accf[lr * 17 + 4 * q + 2];
        a.w = accf[lr * 17 + 4 * q + 3];
        return a;
    };
    int lr0 = (tid >> 2) * 2, lr1 = lr0 + 1;
    int r0g = (d << BSHIFT) + lr0, r1g = r0g + 1;
    float dg0 = 0.f, dg1 = 0.f;
    {
        float4 t0, t1;
        if (fits) {
            row_pull(lr0, H1h, t0, dg0);
            row_pull(lr1, H1h, t1, dg1);
        } else {
            t0 = ld_accf(lr0); dg0 = dacc[lr0];
            t1 = ld_accf(lr1); dg1 = dacc[lr1];
        }
        auto store_Ah = [&](int r, float4 a) {
            a.x = fmaxf(a.x, 0.f); a.y = fmaxf(a.y, 0.f);
            a.z = fmaxf(a.z, 0.f); a.w = fmaxf(a.w, 0.f);
            __half2 o0 = __floats2half2_rn(a.x, a.y);
            __half2 o1 = __floats2half2_rn(a.z, a.w);
            uint2 pk;
            pk.x = *reinterpret_cast<unsigned int*>(&o0);
            pk.y = *reinterpret_cast<unsigned int*>(&o1);
            reinterpret_cast<uint2*>(Ah)[(size_t)r * 4 + q] = pk;
        };
        if (r0g < n) store_Ah(r0g, t0);
        if (r1g < n) store_Ah(r1g, t1);
    }
    grid_sync(bar, gridDim.x);
    if (!fits) {
        for (int i = tid; i < BROWS * 17; i += 512) accf[i] = 0.f;
        __syncthreads();
        const __half2* Ah2 = (const __half2*)Ah;
        for (int p = tid; p < m; p += 512) {
            int blk = bsearch_pfx(u.p1.pfx, p);
            uint2 rec = bin[(size_t)u.p1.gs[blk] + (p - u.p1.pfx[blk])];
            int lr = rec.x >> 24;
            int c = rec.x & 0xFFFFFF;
            float v = __uint_as_float(rec.y);
            const __half2* hp = Ah2 + (size_t)c * 8;
#pragma unroll
            for (int j = 0; j < 8; ++j) {
                float2 f = __half22float2(hp[j]);
                atomicAdd(&accf[lr * 17 + 2 * j], v * f.x);
                atomicAdd(&accf[lr * 17 + 2 * j + 1], v * f.y);
            }
        }
        __syncthreads();
    }
    float4 T0, T1;
    if (fits) {
        float dum0, dum1;
        row_pull(lr0, (const uint2*)Ah, T0, dum0);
        row_pull(lr1, (const uint2*)Ah, T1, dum1);
    } else {
        T0 = ld_accf(lr0);
        T1 = ld_accf(lr1);
    }
    auto epilogue = [&](int r, float4 a0, float dg) {
        int ob = q * 16;
        if (fits) {
            const float4* bp = reinterpret_cast<const float4*>(&u.p2.b2s[ob]);
            float4 c0 = bp[0], c1 = bp[1], c2 = bp[2], c3 = bp[3];
            c0.x *= dg; c0.y *= dg; c0.z *= dg; c0.w *= dg;
            c1.x *= dg; c1.y *= dg; c1.z *= dg; c1.w *= dg;
            c2.x *= dg; c2.y *= dg; c2.z *= dg; c2.w *= dg;
            c3.x *= dg; c3.y *= dg; c3.z *= dg; c3.w *= dg;
#pragma unroll
            for (int sq = 0; sq < 4; ++sq) {
                float tv[4];
                tv[0] = __shfl(a0.x, sq, 4);
                tv[1] = __shfl(a0.y, sq, 4);
                tv[2] = __shfl(a0.z, sq, 4);
                tv[3] = __shfl(a0.w, sq, 4);
#pragma unroll
                for (int j = 0; j < 4; ++j) {
                    int h = 4 * sq + j;
                    const float4* wp = reinterpret_cast<const float4*>(
                        &u.p2.w2[h * OUT_SIZE + ob]);
                    float4 w0 = wp[0], w1 = wp[1], w2v = wp[2], w3 = wp[3];
                    float th = tv[j];
                    c0.x += th * w0.x; c0.y += th * w0.y; c0.z += th * w0.z; c0.w += th * w0.w;
                    c1.x += th * w1.x; c1.y += th * w1.y; c1.z += th * w1.z; c1.w += th * w1.w;
                    c2.x += th * w2v.x; c2.y += th * w2v.y; c2.z += th * w2v.z; c2.w += th * w2v.w;
                    c3.x += th * w3.x; c3.y += th * w3.y; c3.z += th * w3.z; c3.w += th * w3.w;
                }
            }
            c0.x = fmaxf(c0.x, 0.f); c0.y = fmaxf(c0.y, 0.f); c0.z = fmaxf(c0.z, 0.f); c0.w = fmaxf(c0.w, 0.f);
            c1.x = fmaxf(c1.x, 0.f); c1.y = fmaxf(c1.y, 0.f); c1.z = fmaxf(c1.z, 0.f); c1.w = fmaxf(c1.w, 0.f);
            c2.x = fmaxf(c2.x, 0.f); c2.y = fmaxf(c2.y, 0.f); c2.z = fmaxf(c2.z, 0.f); c2.w = fmaxf(c2.w, 0.f);
            c3.x = fmaxf(c3.x, 0.f); c3.y = fmaxf(c3.y, 0.f); c3.z = fmaxf(c3.z, 0.f); c3.w = fmaxf(c3.w, 0.f);
            float4* op = reinterpret_cast<float4*>(out + (size_t)r * OUT_SIZE + ob);
            op[0] = c0; op[1] = c1; op[2] = c2; op[3] = c3;
        } else {
            float oacc[16];
#pragma unroll
            for (int t2 = 0; t2 < 16; ++t2) oacc[t2] = dg * b2[ob + t2];
#pragma unroll
            for (int sq = 0; sq < 4; ++sq) {
                float tv[4];
                tv[0] = __shfl(a0.x, sq, 4);
                tv[1] = __shfl(a0.y, sq, 4);
                tv[2] = __shfl(a0.z, sq, 4);
                tv[3] = __shfl(a0.w, sq, 4);
#pragma unroll
                for (int j = 0; j < 4; ++j) {
                    int h = 4 * sq + j;
#pragma unroll
                    for (int t2 = 0; t2 < 16; ++t2)
                        oacc[t2] += tv[j] * W2[(ob + t2) * HIDDEN + h];
                }
            }
#pragma unroll
            for (int t2 = 0; t2 < 16; ++t2)
                out[(size_t)r * OUT_SIZE + ob + t2] = fmaxf(oacc[t2], 0.f);
        }
    };
    if (r0g < n) epilogue(r0g, T0, dg0);
    if (r1g < n) epilogue(r1g, T1, dg1);
}

static inline char* align_up(char* p, size_t a) {
    return (char*)(((uintptr_t)p + a - 1) & ~(uintptr_t)(a - 1));
}

extern "C" void kernel_launch(void* const* d_in, const int* in_sizes, int n_in,
                              void* d_out, int out_size, void* d_ws, size_t ws_size,
                              hipStream_t stream) {
    const int*   index = (const int*)d_in[0];
    const float* value = (const float*)d_in[1];
    const float* X     = (const float*)d_in[4];
    const float* W1    = (const float*)d_in[5];
    const float* b1    = (const float*)d_in[6];
    const float* W2    = (const float*)d_in[7];
    const float* b2    = (const float*)d_in[8];
    float* out = (float*)d_out;

    long nedges = in_sizes[1];
    int  n      = in_sizes[4] / IN_SIZE;
    const int* row = index;
    const int* col = index + nedges;

    int nblk = (int)((nedges + EB - 1) / EB);
    int ncs  = (n + BROWS - 1) / BROWS;
    int nd1  = (n + 255) / 256;

    size_t need = (size_t)nedges * 8 + (size_t)(NBUCK + 1) * nblk * 4 + 128 +
                  (size_t)n * (32 + 32) + 256;

    if (ws_size >= need && n <= (NBUCK << BSHIFT) && nblk >= 1 &&
        nblk <= NBLK_MAX && ncs <= 512) {
        char* p = (char*)d_ws;
        uint2* bin = (uint2*)p;       p += (size_t)nedges * 8;
        int* dirT  = (int*)p;         p += (size_t)(NBUCK + 1) * nblk * 4;
        p = align_up(p, 64);
        unsigned int* bar = (unsigned int*)p;  p += 64;
        __half2* H1h = (__half2*)p;   p += (size_t)n * 32;
        __half2* Ah  = (__half2*)p;

        hipMemsetAsync(bar, 0, 2 * sizeof(unsigned int), stream);
        prep_kernel<<<nblk + nd1, BINBLK, 0, stream>>>(
            row, col, value, bin, dirT, nblk, nedges, X, W1, b1, H1h, n);
        spmm_fused_kernel<<<ncs, 512, 0, stream>>>(
            bin, dirT, (const uint2*)H1h, Ah, W2, b2, out, bar, n, nblk);
    } else {
        float* ws = (float*)d_ws;
        float* H1  = ws;
        float* S1  = H1 + (size_t)n * HIDDEN;
        float* T   = S1 + (size_t)n * HIDDEN;
        float* deg = T + (size_t)n * HIDDEN;
        zero_int_kernel<<<2048, 256, 0, stream>>>((int*)S1, (long)n * (2 * HIDDEN + 1));
        dense1_kernel<<<(n + 15) / 16, 256, 0, stream>>>(X, W1, b1, H1, n);
        long thr1 = nedges * HIDDEN;
        spmm16_kernel<<<(int)((thr1 + 255) / 256), 256, 0, stream>>>(
            row, col, value, H1, S1, deg, nedges, 0);
        spmm16_kernel<<<(int)((thr1 + 255) / 256), 256, 0, stream>>>(
            row, col, value, S1, T, nullptr, nedges, 1);
        dense2_kernel<<<(n + 3) / 4, 256, 0, stream>>>(T, deg, W2, b2, out, n);
    }
}

// Round 15
// 159.639 us; speedup vs baseline: 1.2497x; 1.2497x over previous
//
#include <hip/hip_runtime.h>
#include <hip/hip_fp16.h>

#define IN_SIZE 256
#define HIDDEN 16
#define OUT_SIZE 64
#define BSHIFT 7            // bucket = row >> 7 (128 rows)
#define BROWS 128
#define NBUCK 1024          // supports n <= 131072
#define EB 8192             // edges per bin block
#define BINBLK 1024
#define EPT 8
#define NBLK_MAX 512        // supports nedges <= 4.19M
#define WSTR 20
#define CAP 4416            // LDS-resident records per 128-row bucket
#define KPT 9               // ceil(CAP/512) records per thread

// ---------------- fallback-path kernels ----------------
__global__ __launch_bounds__(256) void zero_int_kernel(int* __restrict__ a, long n) {
    long i = (long)blockIdx.x * 256 + threadIdx.x;
    long stride = (long)gridDim.x * 256;
    for (; i < n; i += stride) a[i] = 0;
}

__global__ __launch_bounds__(256) void dense1_kernel(
    const float* __restrict__ X, const float* __restrict__ W1,
    const float* __restrict__ b1, float* __restrict__ H1, int n) {
    __shared__ float w[HIDDEN * IN_SIZE];
    for (int i = threadIdx.x; i < HIDDEN * IN_SIZE; i += 256) {
        int h = i >> 8;
        int k = i & 255;
        w[k * HIDDEN + h] = W1[i];
    }
    __syncthreads();
    int t = threadIdx.x;
    int node = blockIdx.x * 16 + (t >> 4);
    int h = t & 15;
    if (node >= n) return;
    const float4* xr = reinterpret_cast<const float4*>(X + (size_t)node * IN_SIZE);
    float acc = b1[h];
#pragma unroll 8
    for (int kk = 0; kk < IN_SIZE / 4; ++kk) {
        float4 x = xr[kk];
        const float* wr = &w[(kk * 4) * HIDDEN + h];
        acc += x.x * wr[0] + x.y * wr[HIDDEN] + x.z * wr[2 * HIDDEN] + x.w * wr[3 * HIDDEN];
    }
    H1[(size_t)node * HIDDEN + h] = acc;
}

__global__ __launch_bounds__(256) void spmm16_kernel(
    const int* __restrict__ row, const int* __restrict__ col,
    const float* __restrict__ val, const float* __restrict__ Hin,
    float* __restrict__ Sout, float* __restrict__ deg, long nedges, int relu_in) {
    long t = (long)blockIdx.x * 256 + threadIdx.x;
    long e = t >> 4;
    if (e >= nedges) return;
    int k = (int)(t & 15);
    int r = row[e];
    int c = col[e];
    float v = val[e];
    float x = Hin[(size_t)c * HIDDEN + k];
    if (relu_in) x = fmaxf(x, 0.0f);
    atomicAdd(&Sout[(size_t)r * HIDDEN + k], v * x);
    if (deg != nullptr && k == 0) atomicAdd(&deg[r], v);
}

__global__ __launch_bounds__(256) void dense2_kernel(
    const float* __restrict__ T, const float* __restrict__ deg,
    const float* __restrict__ W2, const float* __restrict__ b2,
    float* __restrict__ out, int n) {
    __shared__ float w[OUT_SIZE * HIDDEN];
    for (int i = threadIdx.x; i < OUT_SIZE * HIDDEN; i += 256) {
        int o = i / HIDDEN;
        int h = i % HIDDEN;
        w[h * OUT_SIZE + o] = W2[i];
    }
    __syncthreads();
    int node = blockIdx.x * 4 + (threadIdx.x >> 6);
    int o = threadIdx.x & 63;
    if (node >= n) return;
    float acc = deg[node] * b2[o];
#pragma unroll
    for (int h = 0; h < HIDDEN; ++h)
        acc += T[(size_t)node * HIDDEN + h] * w[h * OUT_SIZE + o];
    out[(size_t)node * OUT_SIZE + o] = fmaxf(acc, 0.0f);
}

// ---------------- prep: bin (blocks < nblk) + dense1(fp16) (rest) ----------
// bin: block-major bucket sort + directory (round-13 layout).
// record: x = (lr<<24)|col ; y = val bits
// meta: lr<<25 | bb<<13 | slot  (lr<128, bb<1024, slot<8192; bits 23-24 = 0)
__global__ void prep_kernel(
    const int* __restrict__ row, const int* __restrict__ col,
    const float* __restrict__ val, uint2* __restrict__ bin,
    int* __restrict__ dirT, int nblk, long nedges,
    const float* __restrict__ X, const float* __restrict__ W1,
    const float* __restrict__ b1, __half2* __restrict__ H1, int n) {
    __shared__ union USh {
        struct { int hist[NBUCK]; int lbase[NBUCK]; int s[NBUCK];
                 unsigned int staged[EB * 2]; } b;          // 76 KB
        float w[IN_SIZE * WSTR];                            // 20 KB
    } u;
    int tid = threadIdx.x;
    if (blockIdx.x < nblk) {
        // ---------- bin part (1024 threads) ----------
        int blk = blockIdx.x;
        long base = (long)blk * EB;
        int ecount = (int)(((nedges - base) < (long)EB) ? (nedges - base) : (long)EB);
        u.b.hist[tid] = 0;   // NBUCK == BINBLK
        __syncthreads();
        unsigned int meta[EPT], cc[EPT], vv[EPT];
        if (ecount == EB) {
            long e8 = base + (long)tid * EPT;
            int4 ra = *reinterpret_cast<const int4*>(row + e8);
            int4 rb = *reinterpret_cast<const int4*>(row + e8 + 4);
            int4 ca = *reinterpret_cast<const int4*>(col + e8);
            int4 cb = *reinterpret_cast<const int4*>(col + e8 + 4);
            float4 va = *reinterpret_cast<const float4*>(val + e8);
            float4 vb = *reinterpret_cast<const float4*>(val + e8 + 4);
            int rr[8] = {ra.x, ra.y, ra.z, ra.w, rb.x, rb.y, rb.z, rb.w};
            int cr[8] = {ca.x, ca.y, ca.z, ca.w, cb.x, cb.y, cb.z, cb.w};
            float vr[8] = {va.x, va.y, va.z, va.w, vb.x, vb.y, vb.z, vb.w};
#pragma unroll
            for (int i = 0; i < EPT; ++i) {
                int r = rr[i];
                int bb = r >> BSHIFT;
                int slot = atomicAdd(&u.b.hist[bb], 1);
                meta[i] = ((unsigned int)(r & (BROWS - 1)) << 25) |
                          ((unsigned int)bb << 13) | (unsigned int)slot;
                cc[i] = (unsigned int)cr[i];
                vv[i] = __float_as_uint(vr[i]);
            }
        } else {
#pragma unroll
            for (int i = 0; i < EPT; ++i) {
                int k = tid * EPT + i;
                meta[i] = 0xFFFFFFFFu;
                if (k < ecount) {
                    int r = row[base + k];
                    cc[i] = (unsigned int)col[base + k];
                    vv[i] = __float_as_uint(val[base + k]);
                    int bb = r >> BSHIFT;
                    int slot = atomicAdd(&u.b.hist[bb], 1);
                    meta[i] = ((unsigned int)(r & (BROWS - 1)) << 25) |
                              ((unsigned int)bb << 13) | (unsigned int)slot;
                }
            }
        }
        __syncthreads();
        int x = u.b.hist[tid];
        u.b.s[tid] = x;
        __syncthreads();
        for (int off = 1; off < BINBLK; off <<= 1) {
            int t = (tid >= off) ? u.b.s[tid - off] : 0;
            __syncthreads();
            u.b.s[tid] += t;
            __syncthreads();
        }
        u.b.lbase[tid] = u.b.s[tid] - x;
        __syncthreads();
        for (int i = tid; i <= NBUCK; i += BINBLK)
            dirT[(size_t)i * nblk + blk] = (i < NBUCK) ? u.b.lbase[i] : ecount;
#pragma unroll
        for (int i = 0; i < EPT; ++i) {
            if (meta[i] != 0xFFFFFFFFu) {
                int bb = (int)((meta[i] >> 13) & 0x3FF);
                int p = u.b.lbase[bb] + (int)(meta[i] & 0x1FFF);
                u.b.staged[2 * p]     = ((meta[i] >> 25) << 24) | cc[i];
                u.b.staged[2 * p + 1] = vv[i];
            }
        }
        __syncthreads();
        for (int j = tid; j < ecount; j += BINBLK)
            bin[base + j] = make_uint2(u.b.staged[2 * j], u.b.staged[2 * j + 1]);
    } else {
        // ---------- dense1 part (1024 threads, 256 nodes/block) ----------
        for (int i = tid; i < HIDDEN * IN_SIZE; i += BINBLK) {
            int h = i >> 8;
            int k = i & 255;
            u.w[k * WSTR + h] = W1[i];
        }
        __syncthreads();
        int node = (blockIdx.x - nblk) * 256 + (tid >> 2);
        int q = tid & 3;
        if (node >= n) return;
        float acc[16];
#pragma unroll
        for (int h = 0; h < 16; ++h) acc[h] = 0.f;
        const float4* xr = reinterpret_cast<const float4*>(X + (size_t)node * IN_SIZE);
#pragma unroll 8
        for (int kk = 0; kk < 16; ++kk) {
            float4 x = xr[q + 4 * kk];
            const float* wr = &u.w[(kk * 16 + q * 4) * WSTR];
#pragma unroll
            for (int j = 0; j < 4; ++j) {
                float xs = (j == 0) ? x.x : (j == 1) ? x.y : (j == 2) ? x.z : x.w;
                const float* wj = wr + j * WSTR;
#pragma unroll
                for (int h = 0; h < 16; ++h)
                    acc[h] += xs * wj[h];
            }
        }
#pragma unroll
        for (int h = 0; h < 16; ++h) {
            acc[h] += __shfl_xor(acc[h], 1, 4);
            acc[h] += __shfl_xor(acc[h], 2, 4);
        }
        const float4 bb = reinterpret_cast<const float4*>(b1)[q];
        int hb = q * 4;
        __half2 o0 = __floats2half2_rn(acc[hb] + bb.x, acc[hb + 1] + bb.y);
        __half2 o1 = __floats2half2_rn(acc[hb + 2] + bb.z, acc[hb + 3] + bb.w);
        uint2 pk;
        pk.x = *reinterpret_cast<unsigned int*>(&o0);
        pk.y = *reinterpret_cast<unsigned int*>(&o1);
        reinterpret_cast<uint2*>(H1)[(size_t)node * 4 + q] = pk;
    }
}

// ---------------- shared helpers ----------------
__device__ __forceinline__ int bsearch_pfx(const int* pfx, int p) {
    int lo = 0;
#pragma unroll
    for (int sh = 8; sh >= 0; --sh) {
        int mid = lo + (1 << sh);
        if (mid < NBLK_MAX && pfx[mid] <= p) lo = mid;
    }
    return lo;
}

__device__ __forceinline__ void fma_h(float4& a, uint2 h, float v) {
    __half2 lo = *reinterpret_cast<const __half2*>(&h.x);
    __half2 hi = *reinterpret_cast<const __half2*>(&h.y);
    float2 f0 = __half22float2(lo), f1 = __half22float2(hi);
    a.x += v * f0.x; a.y += v * f0.y; a.z += v * f1.x; a.w += v * f1.y;
}

// ---------------- fused dir-gather + reg-staged sort + spmm1 ---------------
// Ah = relu(spmm(H1h)) fp16, deg; exports sorted records (epackS), per-row
// (sbase,cnt) (mcnt), m (minfo) so pass 2 skips the sort.
__global__ __launch_bounds__(512) void csort_spmm1_kernel(
    const uint2* __restrict__ bin, const int* __restrict__ dirT,
    const uint2* __restrict__ Hin, __half2* __restrict__ Ah,
    float* __restrict__ deg, uint2* __restrict__ epackS,
    unsigned int* __restrict__ mcnt, int* __restrict__ minfo,
    int n, int nblk) {
    __shared__ int gs[NBLK_MAX];
    __shared__ unsigned short rl[NBLK_MAX];
    __shared__ int pfx[NBLK_MAX];
    __shared__ int s[NBLK_MAX];
    __shared__ int cnt[BROWS], sbase[BROWS];
    __shared__ float dacc[BROWS];
    __shared__ int mTot;
    __shared__ uint2 eld[CAP];
    int d = blockIdx.x, tid = threadIdx.x;
    if (tid < nblk) {
        int a = dirT[(size_t)d * nblk + tid];
        int b = dirT[(size_t)(d + 1) * nblk + tid];
        gs[tid] = tid * EB + a;
        rl[tid] = (unsigned short)(b - a);
    } else { gs[tid] = 0; rl[tid] = 0; }
    __syncthreads();
    int x = (int)rl[tid];
    s[tid] = x;
    __syncthreads();
    for (int off = 1; off < NBLK_MAX; off <<= 1) {
        int t = (tid >= off) ? s[tid - off] : 0;
        __syncthreads();
        s[tid] += t;
        __syncthreads();
    }
    pfx[tid] = s[tid] - x;
    if (tid == NBLK_MAX - 1) mTot = s[NBLK_MAX - 1];
    if (tid < BROWS) { cnt[tid] = 0; dacc[tid] = 0.f; }
    __syncthreads();
    int m = mTot;
    bool fits = (m <= CAP);
    if (tid == 0) minfo[d] = m;
    float* accf = (float*)eld;
    if (fits) {
        uint2 regs[KPT];
        unsigned short slot_[KPT];
        unsigned char lr_[KPT];
#pragma unroll
        for (int k = 0; k < KPT; ++k) {
            int p = tid + k * 512;
            if (p < m) {
                int blk = bsearch_pfx(pfx, p);
                uint2 rec = bin[(size_t)gs[blk] + (p - pfx[blk])];
                int lr = rec.x >> 24;
                regs[k] = make_uint2(rec.x & 0xFFFFFF, rec.y);
                slot_[k] = (unsigned short)atomicAdd(&cnt[lr], 1);
                lr_[k] = (unsigned char)lr;
            }
        }
        __syncthreads();
        int cx = (tid < BROWS) ? cnt[tid] : 0;
        if (tid < BROWS) s[tid] = cx;
        __syncthreads();
        for (int off = 1; off < BROWS; off <<= 1) {
            int t = (tid >= off && tid < BROWS) ? s[tid - off] : 0;
            __syncthreads();
            if (tid < BROWS) s[tid] += t;
            __syncthreads();
        }
        if (tid < BROWS) {
            int sb = s[tid] - cx;
            sbase[tid] = sb;
            mcnt[(size_t)d * BROWS + tid] =
                ((unsigned int)sb << 16) | (unsigned int)cx;
        }
        __syncthreads();
#pragma unroll
        for (int k = 0; k < KPT; ++k) {
            int p = tid + k * 512;
            if (p < m) eld[sbase[lr_[k]] + slot_[k]] = regs[k];
        }
        __syncthreads();
        uint2* eg = epackS + (size_t)d * CAP;
        for (int j = tid; j < m; j += 512) eg[j] = eld[j];
    } else {
        for (int i = tid; i < BROWS * 17; i += 512) accf[i] = 0.f;
        __syncthreads();
        for (int p = tid; p < m; p += 512) {
            int blk = bsearch_pfx(pfx, p);
            uint2 rec = bin[(size_t)gs[blk] + (p - pfx[blk])];
            int lr = rec.x >> 24;
            int c = rec.x & 0xFFFFFF;
            float v = __uint_as_float(rec.y);
            const __half2* hp = reinterpret_cast<const __half2*>(Hin + (size_t)c * 4);
#pragma unroll
            for (int j = 0; j < 8; ++j) {
                float2 f = __half22float2(hp[j]);
                atomicAdd(&accf[lr * 17 + 2 * j], v * f.x);
                atomicAdd(&accf[lr * 17 + 2 * j + 1], v * f.y);
            }
            atomicAdd(&dacc[lr], v);
        }
        __syncthreads();
    }
    int lr = tid >> 2, q = tid & 3;
    int r = (d << BSHIFT) + lr;
    if (r >= n) return;
    float4 a0 = {0,0,0,0};
    float dg = 0.f;
    if (fits) {
        float4 a1 = {0,0,0,0}, a2 = {0,0,0,0}, a3 = {0,0,0,0};
        int e = sbase[lr], e1 = e + cnt[lr];
        for (; e + 4 <= e1; e += 4) {
            uint2 r0 = eld[e], r1 = eld[e + 1], r2 = eld[e + 2], r3 = eld[e + 3];
            uint2 h0 = Hin[(size_t)r0.x * 4 + q];
            uint2 h1 = Hin[(size_t)r1.x * 4 + q];
            uint2 h2 = Hin[(size_t)r2.x * 4 + q];
            uint2 h3 = Hin[(size_t)r3.x * 4 + q];
            float v0 = __uint_as_float(r0.y), v1 = __uint_as_float(r1.y);
            float v2 = __uint_as_float(r2.y), v3 = __uint_as_float(r3.y);
            fma_h(a0, h0, v0); fma_h(a1, h1, v1);
            fma_h(a2, h2, v2); fma_h(a3, h3, v3);
            dg += v0 + v1 + v2 + v3;
        }
        for (; e < e1; ++e) {
            uint2 rr = eld[e];
            uint2 h = Hin[(size_t)rr.x * 4 + q];
            float v = __uint_as_float(rr.y);
            fma_h(a0, h, v);
            dg += v;
        }
        a0.x += a1.x + a2.x + a3.x;
        a0.y += a1.y + a2.y + a3.y;
        a0.z += a1.z + a2.z + a3.z;
        a0.w += a1.w + a2.w + a3.w;
    } else {
        a0.x = accf[lr * 17 + 4 * q];
        a0.y = accf[lr * 17 + 4 * q + 1];
        a0.z = accf[lr * 17 + 4 * q + 2];
        a0.w = accf[lr * 17 + 4 * q + 3];
        dg = dacc[lr];
    }
    a0.x = fmaxf(a0.x, 0.f); a0.y = fmaxf(a0.y, 0.f);
    a0.z = fmaxf(a0.z, 0.f); a0.w = fmaxf(a0.w, 0.f);
    __half2 o0 = __floats2half2_rn(a0.x, a0.y);
    __half2 o1 = __floats2half2_rn(a0.z, a0.w);
    uint2 pk;
    pk.x = *reinterpret_cast<unsigned int*>(&o0);
    pk.y = *reinterpret_cast<unsigned int*>(&o1);
    reinterpret_cast<uint2*>(Ah)[(size_t)r * 4 + q] = pk;
    if (q == 0) deg[r] = dg;
}

// ---------------- fused spmm2 + dense2 (sort-free fits path) ---------------
__global__ __launch_bounds__(512) void spmm2_out_kernel(
    const uint2* __restrict__ bin, const int* __restrict__ dirT,
    const uint2* __restrict__ epackS, const unsigned int* __restrict__ mcnt,
    const int* __restrict__ minfo, const uint2* __restrict__ Hin,
    const float* __restrict__ W2, const float* __restrict__ b2,
    const float* __restrict__ deg, float* __restrict__ out,
    int n, int nblk) {
    __shared__ int gs[NBLK_MAX];
    __shared__ unsigned short rl[NBLK_MAX];
    __shared__ int pfx[NBLK_MAX];
    __shared__ int s[NBLK_MAX];
    __shared__ int cnt[BROWS], sbase[BROWS];
    __shared__ int sh_m;
    __shared__ float w2[HIDDEN * OUT_SIZE];
    __shared__ float b2s[OUT_SIZE];
    __shared__ uint2 eld[CAP];
    int d = blockIdx.x, tid = threadIdx.x;
    for (int i = tid; i < HIDDEN * OUT_SIZE; i += 512)
        w2[(i & 15) * OUT_SIZE + (i >> 4)] = W2[i];
    if (tid < OUT_SIZE) b2s[tid] = b2[tid];
    if (tid == 0) sh_m = minfo[d];
    __syncthreads();
    int m = sh_m;
    bool fits = (m <= CAP);
    float* accf = (float*)eld;
    if (fits) {
        if (tid < BROWS) {
            unsigned int mc = mcnt[(size_t)d * BROWS + tid];
            sbase[tid] = (int)(mc >> 16);
            cnt[tid] = (int)(mc & 0xFFFF);
        }
        const uint2* eg = epackS + (size_t)d * CAP;
        for (int j = tid; j < m; j += 512) eld[j] = eg[j];
        __syncthreads();
    } else {
        if (tid < nblk) {
            int a = dirT[(size_t)d * nblk + tid];
            int b = dirT[(size_t)(d + 1) * nblk + tid];
            gs[tid] = tid * EB + a;
            rl[tid] = (unsigned short)(b - a);
        } else { gs[tid] = 0; rl[tid] = 0; }
        __syncthreads();
        int x = (int)rl[tid];
        s[tid] = x;
        __syncthreads();
        for (int off = 1; off < NBLK_MAX; off <<= 1) {
            int t = (tid >= off) ? s[tid - off] : 0;
            __syncthreads();
            s[tid] += t;
            __syncthreads();
        }
        pfx[tid] = s[tid] - x;
        __syncthreads();
        for (int i = tid; i < BROWS * 17; i += 512) accf[i] = 0.f;
        __syncthreads();
        for (int p = tid; p < m; p += 512) {
            int blk = bsearch_pfx(pfx, p);
            uint2 rec = bin[(size_t)gs[blk] + (p - pfx[blk])];
            int lr = rec.x >> 24;
            int c = rec.x & 0xFFFFFF;
            float v = __uint_as_float(rec.y);
            const __half2* hp = reinterpret_cast<const __half2*>(Hin + (size_t)c * 4);
#pragma unroll
            for (int j = 0; j < 8; ++j) {
                float2 f = __half22float2(hp[j]);
                atomicAdd(&accf[lr * 17 + 2 * j], v * f.x);
                atomicAdd(&accf[lr * 17 + 2 * j + 1], v * f.y);
            }
        }
        __syncthreads();
    }
    int lr = tid >> 2, q = tid & 3;
    int r = (d << BSHIFT) + lr;
    if (r >= n) return;
    float4 a0 = {0,0,0,0};
    if (fits) {
        float4 a1 = {0,0,0,0}, a2 = {0,0,0,0}, a3 = {0,0,0,0};
        int e = sbase[lr], e1 = e + cnt[lr];
        for (; e + 4 <= e1; e += 4) {
            uint2 r0 = eld[e], r1 = eld[e + 1], r2 = eld[e + 2], r3 = eld[e + 3];
            uint2 h0 = Hin[(size_t)r0.x * 4 + q];
            uint2 h1 = Hin[(size_t)r1.x * 4 + q];
            uint2 h2 = Hin[(size_t)r2.x * 4 + q];
            uint2 h3 = Hin[(size_t)r3.x * 4 + q];
            fma_h(a0, h0, __uint_as_float(r0.y));
            fma_h(a1, h1, __uint_as_float(r1.y));
            fma_h(a2, h2, __uint_as_float(r2.y));
            fma_h(a3, h3, __uint_as_float(r3.y));
        }
        for (; e < e1; ++e) {
            uint2 rr = eld[e];
            uint2 h = Hin[(size_t)rr.x * 4 + q];
            fma_h(a0, h, __uint_as_float(rr.y));
        }
        a0.x += a1.x + a2.x + a3.x;
        a0.y += a1.y + a2.y + a3.y;
        a0.z += a1.z + a2.z + a3.z;
        a0.w += a1.w + a2.w + a3.w;
    } else {
        a0.x = accf[lr * 17 + 4 * q];
        a0.y = accf[lr * 17 + 4 * q + 1];
        a0.z = accf[lr * 17 + 4 * q + 2];
        a0.w = accf[lr * 17 + 4 * q + 3];
    }
    float dg = deg[r];
    int ob = q * 16;
    const float4* bp = reinterpret_cast<const float4*>(&b2s[ob]);
    float4 c0 = bp[0], c1 = bp[1], c2 = bp[2], c3 = bp[3];
    c0.x *= dg; c0.y *= dg; c0.z *= dg; c0.w *= dg;
    c1.x *= dg; c1.y *= dg; c1.z *= dg; c1.w *= dg;
    c2.x *= dg; c2.y *= dg; c2.z *= dg; c2.w *= dg;
    c3.x *= dg; c3.y *= dg; c3.z *= dg; c3.w *= dg;
#pragma unroll
    for (int sq = 0; sq < 4; ++sq) {
        float tv[4];
        tv[0] = __shfl(a0.x, sq, 4);
        tv[1] = __shfl(a0.y, sq, 4);
        tv[2] = __shfl(a0.z, sq, 4);
        tv[3] = __shfl(a0.w, sq, 4);
#pragma unroll
        for (int j = 0; j < 4; ++j) {
            int h = 4 * sq + j;
            const float4* wp = reinterpret_cast<const float4*>(&w2[h * OUT_SIZE + ob]);
            float4 w0 = wp[0], w1 = wp[1], w2v = wp[2], w3 = wp[3];
            float th = tv[j];
            c0.x += th * w0.x; c0.y += th * w0.y; c0.z += th * w0.z; c0.w += th * w0.w;
            c1.x += th * w1.x; c1.y += th * w1.y; c1.z += th * w1.z; c1.w += th * w1.w;
            c2.x += th * w2v.x; c2.y += th * w2v.y; c2.z += th * w2v.z; c2.w += th * w2v.w;
            c3.x += th * w3.x; c3.y += th * w3.y; c3.z += th * w3.z; c3.w += th * w3.w;
        }
    }
    c0.x = fmaxf(c0.x, 0.f); c0.y = fmaxf(c0.y, 0.f); c0.z = fmaxf(c0.z, 0.f); c0.w = fmaxf(c0.w, 0.f);
    c1.x = fmaxf(c1.x, 0.f); c1.y = fmaxf(c1.y, 0.f); c1.z = fmaxf(c1.z, 0.f); c1.w = fmaxf(c1.w, 0.f);
    c2.x = fmaxf(c2.x, 0.f); c2.y = fmaxf(c2.y, 0.f); c2.z = fmaxf(c2.z, 0.f); c2.w = fmaxf(c2.w, 0.f);
    c3.x = fmaxf(c3.x, 0.f); c3.y = fmaxf(c3.y, 0.f); c3.z = fmaxf(c3.z, 0.f); c3.w = fmaxf(c3.w, 0.f);
    float4* op = reinterpret_cast<float4*>(out + (size_t)r * OUT_SIZE + ob);
    op[0] = c0; op[1] = c1; op[2] = c2; op[3] = c3;
}

static inline char* align_up(char* p, size_t a) {
    return (char*)(((uintptr_t)p + a - 1) & ~(uintptr_t)(a - 1));
}

extern "C" void kernel_launch(void* const* d_in, const int* in_sizes, int n_in,
                              void* d_out, int out_size, void* d_ws, size_t ws_size,
                              hipStream_t stream) {
    const int*   index = (const int*)d_in[0];
    const float* value = (const float*)d_in[1];
    const float* X     = (const float*)d_in[4];
    const float* W1    = (const float*)d_in[5];
    const float* b1    = (const float*)d_in[6];
    const float* W2    = (const float*)d_in[7];
    const float* b2    = (const float*)d_in[8];
    float* out = (float*)d_out;

    long nedges = in_sizes[1];
    int  n      = in_sizes[4] / IN_SIZE;
    const int* row = index;
    const int* col = index + nedges;

    int nblk = (int)((nedges + EB - 1) / EB);
    int ncs  = (n + BROWS - 1) >> BSHIFT;
    int nd1  = (n + 255) / 256;

    // ws: bin | dirT | epackS[ncs*CAP u2] | mcnt[ncs*128] | minfo[ncs] |
    //     H1h | Ah | deg
    size_t need = (size_t)nedges * 8 + (size_t)(NBUCK + 1) * nblk * 4 +
                  (size_t)ncs * CAP * 8 + (size_t)ncs * BROWS * 4 +
                  (size_t)ncs * 4 + (size_t)n * (32 + 32 + 4) + 1024;

    if (ws_size >= need && n <= (NBUCK << BSHIFT) && nblk <= NBLK_MAX) {
        char* p = (char*)d_ws;
        uint2* bin = (uint2*)p;       p += (size_t)nedges * 8;
        int* dirT  = (int*)p;         p += (size_t)(NBUCK + 1) * nblk * 4;
        uint2* epackS = (uint2*)p;    p += (size_t)ncs * CAP * 8;
        unsigned int* mcnt = (unsigned int*)p;  p += (size_t)ncs * BROWS * 4;
        int* minfo = (int*)p;         p += (size_t)ncs * 4;
        p = align_up(p, 64);
        __half2* H1h = (__half2*)p;   p += (size_t)n * 32;
        __half2* Ah  = (__half2*)p;   p += (size_t)n * 32;
        float* deg   = (float*)p;

        // bin + dense1 overlapped in one heterogeneous launch
        prep_kernel<<<nblk + nd1, BINBLK, 0, stream>>>(
            row, col, value, bin, dirT, nblk, nedges, X, W1, b1, H1h, n);
        csort_spmm1_kernel<<<ncs, 512, 0, stream>>>(
            bin, dirT, (const uint2*)H1h, Ah, deg, epackS, mcnt, minfo, n, nblk);
        spmm2_out_kernel<<<ncs, 512, 0, stream>>>(
            bin, dirT, epackS, mcnt, minfo, (const uint2*)Ah, W2, b2, deg,
            out, n, nblk);
    } else {
        float* ws = (float*)d_ws;
        float* H1  = ws;
        float* S1  = H1 + (size_t)n * HIDDEN;
        float* T   = S1 + (size_t)n * HIDDEN;
        float* deg = T + (size_t)n * HIDDEN;
        zero_int_kernel<<<2048, 256, 0, stream>>>((int*)S1, (long)n * (2 * HIDDEN + 1));
        dense1_kernel<<<(n + 15) / 16, 256, 0, stream>>>(X, W1, b1, H1, n);
        long thr1 = nedges * HIDDEN;
        spmm16_kernel<<<(int)((thr1 + 255) / 256), 256, 0, stream>>>(
            row, col, value, H1, S1, deg, nedges, 0);
        spmm16_kernel<<<(int)((thr1 + 255) / 256), 256, 0, stream>>>(
            row, col, value, S1, T, nullptr, nedges, 1);
        dense2_kernel<<<(n + 3) / 4, 256, 0, stream>>>(T, deg, W2, b2, out, n);
    }
}

// Round 16
// 122.953 us; speedup vs baseline: 1.6226x; 1.2984x over previous
//
#include <hip/hip_runtime.h>
#include <hip/hip_fp16.h>

#define IN_SIZE 256
#define HIDDEN 16
#define OUT_SIZE 64
#define BSHIFT 7            // bucket = row >> 7 (128 rows)
#define BROWS 128
#define NBUCK 1024          // supports n <= 131072
#define EB 8192             // edges per bin block
#define BINBLK 1024
#define EPT 8
#define NBLK_MAX 512        // supports nedges <= 4.19M
#define WSTR 20
#define CAP 4416            // LDS-resident records per 128-row bucket
#define KPT 9               // ceil(CAP/512) records per thread

// ---------------- zero (fallback path) ----------------
__global__ __launch_bounds__(256) void zero_int_kernel(int* __restrict__ a, long n) {
    long i = (long)blockIdx.x * 256 + threadIdx.x;
    long stride = (long)gridDim.x * 256;
    for (; i < n; i += stride) a[i] = 0;
}

// ---------------- H1(fp16) = X @ W1^T + b1  [n,16] ----------------
__global__ __launch_bounds__(256) void dense1_half_kernel(
    const float* __restrict__ X, const float* __restrict__ W1,
    const float* __restrict__ b1, __half2* __restrict__ H1, int n) {
    __shared__ float w[IN_SIZE * WSTR];  // w[k*20+h] = W1[h][k]
    for (int i = threadIdx.x; i < HIDDEN * IN_SIZE; i += 256) {
        int h = i >> 8;
        int k = i & 255;
        w[k * WSTR + h] = W1[i];
    }
    __syncthreads();
    int node = blockIdx.x * 64 + (threadIdx.x >> 2);
    int q = threadIdx.x & 3;
    if (node >= n) return;
    float acc[16];
#pragma unroll
    for (int h = 0; h < 16; ++h) acc[h] = 0.f;
    const float4* xr = reinterpret_cast<const float4*>(X + (size_t)node * IN_SIZE);
#pragma unroll 8
    for (int kk = 0; kk < 16; ++kk) {
        float4 x = xr[q + 4 * kk];
        const float* wr = &w[(kk * 16 + q * 4) * WSTR];
#pragma unroll
        for (int j = 0; j < 4; ++j) {
            float xs = (j == 0) ? x.x : (j == 1) ? x.y : (j == 2) ? x.z : x.w;
            const float* wj = wr + j * WSTR;
#pragma unroll
            for (int h = 0; h < 16; ++h)
                acc[h] += xs * wj[h];
        }
    }
#pragma unroll
    for (int h = 0; h < 16; ++h) {
        acc[h] += __shfl_xor(acc[h], 1, 4);
        acc[h] += __shfl_xor(acc[h], 2, 4);
    }
    const float4 bb = reinterpret_cast<const float4*>(b1)[q];
    int hb = q * 4;
    __half2 o0 = __floats2half2_rn(acc[hb] + bb.x, acc[hb + 1] + bb.y);
    __half2 o1 = __floats2half2_rn(acc[hb + 2] + bb.z, acc[hb + 3] + bb.w);
    uint2 pk;
    pk.x = *reinterpret_cast<unsigned int*>(&o0);
    pk.y = *reinterpret_cast<unsigned int*>(&o1);
    reinterpret_cast<uint2*>(H1)[(size_t)node * 4 + q] = pk;
}

// ---------------- fp32 dense1 (fallback only) ----------------
__global__ __launch_bounds__(256) void dense1_kernel(
    const float* __restrict__ X, const float* __restrict__ W1,
    const float* __restrict__ b1, float* __restrict__ H1, int n) {
    __shared__ float w[HIDDEN * IN_SIZE];
    for (int i = threadIdx.x; i < HIDDEN * IN_SIZE; i += 256) {
        int h = i >> 8;
        int k = i & 255;
        w[k * HIDDEN + h] = W1[i];
    }
    __syncthreads();
    int t = threadIdx.x;
    int node = blockIdx.x * 16 + (t >> 4);
    int h = t & 15;
    if (node >= n) return;
    const float4* xr = reinterpret_cast<const float4*>(X + (size_t)node * IN_SIZE);
    float acc = b1[h];
#pragma unroll 8
    for (int kk = 0; kk < IN_SIZE / 4; ++kk) {
        float4 x = xr[kk];
        const float* wr = &w[(kk * 4) * HIDDEN + h];
        acc += x.x * wr[0] + x.y * wr[HIDDEN] + x.z * wr[2 * HIDDEN] + x.w * wr[3 * HIDDEN];
    }
    H1[(size_t)node * HIDDEN + h] = acc;
}

// ---------------- bin: block-major bucket sort + directory ----------------
__global__ __launch_bounds__(BINBLK) void bin_kernel(
    const int* __restrict__ row, const int* __restrict__ col,
    const float* __restrict__ val, uint2* __restrict__ bin,
    int* __restrict__ dirT, int nblk, long nedges) {
    __shared__ int hist[NBUCK];
    __shared__ int lbase[NBUCK];
    __shared__ int s[BINBLK];
    __shared__ unsigned int staged[EB * 2];   // 64 KB
    int blk = blockIdx.x, tid = threadIdx.x;
    long base = (long)blk * EB;
    int ecount = (int)(((nedges - base) < (long)EB) ? (nedges - base) : (long)EB);
    hist[tid] = 0;
    __syncthreads();
    unsigned int meta[EPT], cc[EPT], vv[EPT];
    if (ecount == EB) {
        long e8 = base + (long)tid * EPT;
        int4 ra = *reinterpret_cast<const int4*>(row + e8);
        int4 rb = *reinterpret_cast<const int4*>(row + e8 + 4);
        int4 ca = *reinterpret_cast<const int4*>(col + e8);
        int4 cb = *reinterpret_cast<const int4*>(col + e8 + 4);
        float4 va = *reinterpret_cast<const float4*>(val + e8);
        float4 vb = *reinterpret_cast<const float4*>(val + e8 + 4);
        int rr[8] = {ra.x, ra.y, ra.z, ra.w, rb.x, rb.y, rb.z, rb.w};
        int cr[8] = {ca.x, ca.y, ca.z, ca.w, cb.x, cb.y, cb.z, cb.w};
        float vr[8] = {va.x, va.y, va.z, va.w, vb.x, vb.y, vb.z, vb.w};
#pragma unroll
        for (int i = 0; i < EPT; ++i) {
            int r = rr[i];
            int bb = r >> BSHIFT;
            int slot = atomicAdd(&hist[bb], 1);
            meta[i] = ((unsigned int)(r & (BROWS - 1)) << 25) |
                      ((unsigned int)bb << 13) | (unsigned int)slot;
            cc[i] = (unsigned int)cr[i];
            vv[i] = __float_as_uint(vr[i]);
        }
    } else {
#pragma unroll
        for (int i = 0; i < EPT; ++i) {
            int k = tid * EPT + i;
            meta[i] = 0xFFFFFFFFu;
            if (k < ecount) {
                int r = row[base + k];
                cc[i] = (unsigned int)col[base + k];
                vv[i] = __float_as_uint(val[base + k]);
                int bb = r >> BSHIFT;
                int slot = atomicAdd(&hist[bb], 1);
                meta[i] = ((unsigned int)(r & (BROWS - 1)) << 25) |
                          ((unsigned int)bb << 13) | (unsigned int)slot;
            }
        }
    }
    __syncthreads();
    int x = hist[tid];
    s[tid] = x;
    __syncthreads();
    for (int off = 1; off < BINBLK; off <<= 1) {
        int t = (tid >= off) ? s[tid - off] : 0;
        __syncthreads();
        s[tid] += t;
        __syncthreads();
    }
    lbase[tid] = s[tid] - x;
    __syncthreads();
    for (int i = tid; i <= NBUCK; i += BINBLK)
        dirT[(size_t)i * nblk + blk] = (i < NBUCK) ? lbase[i] : ecount;
#pragma unroll
    for (int i = 0; i < EPT; ++i) {
        if (meta[i] != 0xFFFFFFFFu) {
            int bb = (int)((meta[i] >> 13) & 0x3FF);
            int p = lbase[bb] + (int)(meta[i] & 0x1FFF);
            staged[2 * p]     = ((meta[i] >> 25) << 24) | cc[i];
            staged[2 * p + 1] = vv[i];
        }
    }
    __syncthreads();
    for (int j = tid; j < ecount; j += BINBLK)
        bin[base + j] = make_uint2(staged[2 * j], staged[2 * j + 1]);
}

// ---------------- shared helpers ----------------
__device__ __forceinline__ int bsearch_pfx(const int* pfx, int p) {
    int lo = 0;
#pragma unroll
    for (int sh = 8; sh >= 0; --sh) {
        int mid = lo + (1 << sh);
        if (mid < NBLK_MAX && pfx[mid] <= p) lo = mid;
    }
    return lo;
}

__device__ __forceinline__ void fma_h(float4& a, uint2 h, float v) {
    __half2 lo = *reinterpret_cast<const __half2*>(&h.x);
    __half2 hi = *reinterpret_cast<const __half2*>(&h.y);
    float2 f0 = __half22float2(lo), f1 = __half22float2(hi);
    a.x += v * f0.x; a.y += v * f0.y; a.z += v * f1.x; a.w += v * f1.y;
}

// ---------------- fused dir-gather + reg-staged sort + spmm1 ---------------
__global__ __launch_bounds__(512) void csort_spmm1_kernel(
    const uint2* __restrict__ bin, const int* __restrict__ dirT,
    const uint2* __restrict__ Hin, __half2* __restrict__ Ah,
    float* __restrict__ deg, uint2* __restrict__ epackS,
    unsigned int* __restrict__ mcnt, int* __restrict__ minfo,
    int n, int nblk) {
    __shared__ int gs[NBLK_MAX];
    __shared__ unsigned short rl[NBLK_MAX];
    __shared__ int pfx[NBLK_MAX];
    __shared__ int s[NBLK_MAX];
    __shared__ int cnt[BROWS], sbase[BROWS];
    __shared__ float dacc[BROWS];
    __shared__ int mTot;
    __shared__ uint2 eld[CAP];
    int d = blockIdx.x, tid = threadIdx.x;
    if (tid < nblk) {
        int a = dirT[(size_t)d * nblk + tid];
        int b = dirT[(size_t)(d + 1) * nblk + tid];
        gs[tid] = tid * EB + a;
        rl[tid] = (unsigned short)(b - a);
    } else { gs[tid] = 0; rl[tid] = 0; }
    __syncthreads();
    int x = (int)rl[tid];
    s[tid] = x;
    __syncthreads();
    for (int off = 1; off < NBLK_MAX; off <<= 1) {
        int t = (tid >= off) ? s[tid - off] : 0;
        __syncthreads();
        s[tid] += t;
        __syncthreads();
    }
    pfx[tid] = s[tid] - x;
    if (tid == NBLK_MAX - 1) mTot = s[NBLK_MAX - 1];
    if (tid < BROWS) { cnt[tid] = 0; dacc[tid] = 0.f; }
    __syncthreads();
    int m = mTot;
    bool fits = (m <= CAP);
    if (tid == 0) minfo[d] = m;
    float* accf = (float*)eld;
    if (fits) {
        uint2 regs[KPT];
        unsigned short slot_[KPT];
        unsigned char lr_[KPT];
#pragma unroll
        for (int k = 0; k < KPT; ++k) {
            int p = tid + k * 512;
            if (p < m) {
                int blk = bsearch_pfx(pfx, p);
                uint2 rec = bin[(size_t)gs[blk] + (p - pfx[blk])];
                int lr = rec.x >> 24;
                regs[k] = make_uint2(rec.x & 0xFFFFFF, rec.y);
                slot_[k] = (unsigned short)atomicAdd(&cnt[lr], 1);
                lr_[k] = (unsigned char)lr;
            }
        }
        __syncthreads();
        int cx = (tid < BROWS) ? cnt[tid] : 0;
        if (tid < BROWS) s[tid] = cx;
        __syncthreads();
        for (int off = 1; off < BROWS; off <<= 1) {
            int t = (tid >= off && tid < BROWS) ? s[tid - off] : 0;
            __syncthreads();
            if (tid < BROWS) s[tid] += t;
            __syncthreads();
        }
        if (tid < BROWS) {
            int sb = s[tid] - cx;
            sbase[tid] = sb;
            mcnt[(size_t)d * BROWS + tid] =
                ((unsigned int)sb << 16) | (unsigned int)cx;
        }
        __syncthreads();
#pragma unroll
        for (int k = 0; k < KPT; ++k) {
            int p = tid + k * 512;
            if (p < m) eld[sbase[lr_[k]] + slot_[k]] = regs[k];
        }
        __syncthreads();
        uint2* eg = epackS + (size_t)d * CAP;
        for (int j = tid; j < m; j += 512) eg[j] = eld[j];
    } else {
        for (int i = tid; i < BROWS * 17; i += 512) accf[i] = 0.f;
        __syncthreads();
        for (int p = tid; p < m; p += 512) {
            int blk = bsearch_pfx(pfx, p);
            uint2 rec = bin[(size_t)gs[blk] + (p - pfx[blk])];
            int lr = rec.x >> 24;
            int c = rec.x & 0xFFFFFF;
            float v = __uint_as_float(rec.y);
            const __half2* hp = reinterpret_cast<const __half2*>(Hin + (size_t)c * 4);
#pragma unroll
            for (int j = 0; j < 8; ++j) {
                float2 f = __half22float2(hp[j]);
                atomicAdd(&accf[lr * 17 + 2 * j], v * f.x);
                atomicAdd(&accf[lr * 17 + 2 * j + 1], v * f.y);
            }
            atomicAdd(&dacc[lr], v);
        }
        __syncthreads();
    }
    int lr = tid >> 2, q = tid & 3;
    int r = (d << BSHIFT) + lr;
    if (r >= n) return;
    float4 a0 = {0,0,0,0};
    float dg = 0.f;
    if (fits) {
        float4 a1 = {0,0,0,0}, a2 = {0,0,0,0}, a3 = {0,0,0,0};
        int e = sbase[lr], e1 = e + cnt[lr];
        // 8-deep independent gather chains for latency hiding
        for (; e + 8 <= e1; e += 8) {
            uint2 r0 = eld[e],     r1 = eld[e + 1], r2 = eld[e + 2], r3 = eld[e + 3];
            uint2 r4 = eld[e + 4], r5 = eld[e + 5], r6 = eld[e + 6], r7 = eld[e + 7];
            uint2 h0 = Hin[(size_t)r0.x * 4 + q];
            uint2 h1 = Hin[(size_t)r1.x * 4 + q];
            uint2 h2 = Hin[(size_t)r2.x * 4 + q];
            uint2 h3 = Hin[(size_t)r3.x * 4 + q];
            uint2 h4 = Hin[(size_t)r4.x * 4 + q];
            uint2 h5 = Hin[(size_t)r5.x * 4 + q];
            uint2 h6 = Hin[(size_t)r6.x * 4 + q];
            uint2 h7 = Hin[(size_t)r7.x * 4 + q];
            float v0 = __uint_as_float(r0.y), v1 = __uint_as_float(r1.y);
            float v2 = __uint_as_float(r2.y), v3 = __uint_as_float(r3.y);
            float v4 = __uint_as_float(r4.y), v5 = __uint_as_float(r5.y);
            float v6 = __uint_as_float(r6.y), v7 = __uint_as_float(r7.y);
            fma_h(a0, h0, v0); fma_h(a1, h1, v1);
            fma_h(a2, h2, v2); fma_h(a3, h3, v3);
            fma_h(a0, h4, v4); fma_h(a1, h5, v5);
            fma_h(a2, h6, v6); fma_h(a3, h7, v7);
            dg += v0 + v1 + v2 + v3 + v4 + v5 + v6 + v7;
        }
        for (; e + 4 <= e1; e += 4) {
            uint2 r0 = eld[e], r1 = eld[e + 1], r2 = eld[e + 2], r3 = eld[e + 3];
            uint2 h0 = Hin[(size_t)r0.x * 4 + q];
            uint2 h1 = Hin[(size_t)r1.x * 4 + q];
            uint2 h2 = Hin[(size_t)r2.x * 4 + q];
            uint2 h3 = Hin[(size_t)r3.x * 4 + q];
            float v0 = __uint_as_float(r0.y), v1 = __uint_as_float(r1.y);
            float v2 = __uint_as_float(r2.y), v3 = __uint_as_float(r3.y);
            fma_h(a0, h0, v0); fma_h(a1, h1, v1);
            fma_h(a2, h2, v2); fma_h(a3, h3, v3);
            dg += v0 + v1 + v2 + v3;
        }
        for (; e < e1; ++e) {
            uint2 rr = eld[e];
            uint2 h = Hin[(size_t)rr.x * 4 + q];
            float v = __uint_as_float(rr.y);
            fma_h(a0, h, v);
            dg += v;
        }
        a0.x += a1.x + a2.x + a3.x;
        a0.y += a1.y + a2.y + a3.y;
        a0.z += a1.z + a2.z + a3.z;
        a0.w += a1.w + a2.w + a3.w;
    } else {
        a0.x = accf[lr * 17 + 4 * q];
        a0.y = accf[lr * 17 + 4 * q + 1];
        a0.z = accf[lr * 17 + 4 * q + 2];
        a0.w = accf[lr * 17 + 4 * q + 3];
        dg = dacc[lr];
    }
    a0.x = fmaxf(a0.x, 0.f); a0.y = fmaxf(a0.y, 0.f);
    a0.z = fmaxf(a0.z, 0.f); a0.w = fmaxf(a0.w, 0.f);
    __half2 o0 = __floats2half2_rn(a0.x, a0.y);
    __half2 o1 = __floats2half2_rn(a0.z, a0.w);
    uint2 pk;
    pk.x = *reinterpret_cast<unsigned int*>(&o0);
    pk.y = *reinterpret_cast<unsigned int*>(&o1);
    reinterpret_cast<uint2*>(Ah)[(size_t)r * 4 + q] = pk;
    if (q == 0) deg[r] = dg;
}

// ---------------- fused spmm2 + dense2 (sort-free fits path) ---------------
__global__ __launch_bounds__(512) void spmm2_out_kernel(
    const uint2* __restrict__ bin, const int* __restrict__ dirT,
    const uint2* __restrict__ epackS, const unsigned int* __restrict__ mcnt,
    const int* __restrict__ minfo, const uint2* __restrict__ Hin,
    const float* __restrict__ W2, const float* __restrict__ b2,
    const float* __restrict__ deg, float* __restrict__ out,
    int n, int nblk) {
    __shared__ int gs[NBLK_MAX];
    __shared__ unsigned short rl[NBLK_MAX];
    __shared__ int pfx[NBLK_MAX];
    __shared__ int s[NBLK_MAX];
    __shared__ int cnt[BROWS], sbase[BROWS];
    __shared__ int sh_m;
    __shared__ float w2[HIDDEN * OUT_SIZE];
    __shared__ float b2s[OUT_SIZE];
    __shared__ uint2 eld[CAP];
    int d = blockIdx.x, tid = threadIdx.x;
    for (int i = tid; i < HIDDEN * OUT_SIZE; i += 512)
        w2[(i & 15) * OUT_SIZE + (i >> 4)] = W2[i];
    if (tid < OUT_SIZE) b2s[tid] = b2[tid];
    if (tid == 0) sh_m = minfo[d];
    __syncthreads();
    int m = sh_m;
    bool fits = (m <= CAP);
    float* accf = (float*)eld;
    if (fits) {
        if (tid < BROWS) {
            unsigned int mc = mcnt[(size_t)d * BROWS + tid];
            sbase[tid] = (int)(mc >> 16);
            cnt[tid] = (int)(mc & 0xFFFF);
        }
        const uint2* eg = epackS + (size_t)d * CAP;
        for (int j = tid; j < m; j += 512) eld[j] = eg[j];
        __syncthreads();
    } else {
        if (tid < nblk) {
            int a = dirT[(size_t)d * nblk + tid];
            int b = dirT[(size_t)(d + 1) * nblk + tid];
            gs[tid] = tid * EB + a;
            rl[tid] = (unsigned short)(b - a);
        } else { gs[tid] = 0; rl[tid] = 0; }
        __syncthreads();
        int x = (int)rl[tid];
        s[tid] = x;
        __syncthreads();
        for (int off = 1; off < NBLK_MAX; off <<= 1) {
            int t = (tid >= off) ? s[tid - off] : 0;
            __syncthreads();
            s[tid] += t;
            __syncthreads();
        }
        pfx[tid] = s[tid] - x;
        __syncthreads();
        for (int i = tid; i < BROWS * 17; i += 512) accf[i] = 0.f;
        __syncthreads();
        for (int p = tid; p < m; p += 512) {
            int blk = bsearch_pfx(pfx, p);
            uint2 rec = bin[(size_t)gs[blk] + (p - pfx[blk])];
            int lr = rec.x >> 24;
            int c = rec.x & 0xFFFFFF;
            float v = __uint_as_float(rec.y);
            const __half2* hp = reinterpret_cast<const __half2*>(Hin + (size_t)c * 4);
#pragma unroll
            for (int j = 0; j < 8; ++j) {
                float2 f = __half22float2(hp[j]);
                atomicAdd(&accf[lr * 17 + 2 * j], v * f.x);
                atomicAdd(&accf[lr * 17 + 2 * j + 1], v * f.y);
            }
        }
        __syncthreads();
    }
    int lr = tid >> 2, q = tid & 3;
    int r = (d << BSHIFT) + lr;
    if (r >= n) return;
    float4 a0 = {0,0,0,0};
    if (fits) {
        float4 a1 = {0,0,0,0}, a2 = {0,0,0,0}, a3 = {0,0,0,0};
        int e = sbase[lr], e1 = e + cnt[lr];
        for (; e + 8 <= e1; e += 8) {
            uint2 r0 = eld[e],     r1 = eld[e + 1], r2 = eld[e + 2], r3 = eld[e + 3];
            uint2 r4 = eld[e + 4], r5 = eld[e + 5], r6 = eld[e + 6], r7 = eld[e + 7];
            uint2 h0 = Hin[(size_t)r0.x * 4 + q];
            uint2 h1 = Hin[(size_t)r1.x * 4 + q];
            uint2 h2 = Hin[(size_t)r2.x * 4 + q];
            uint2 h3 = Hin[(size_t)r3.x * 4 + q];
            uint2 h4 = Hin[(size_t)r4.x * 4 + q];
            uint2 h5 = Hin[(size_t)r5.x * 4 + q];
            uint2 h6 = Hin[(size_t)r6.x * 4 + q];
            uint2 h7 = Hin[(size_t)r7.x * 4 + q];
            fma_h(a0, h0, __uint_as_float(r0.y));
            fma_h(a1, h1, __uint_as_float(r1.y));
            fma_h(a2, h2, __uint_as_float(r2.y));
            fma_h(a3, h3, __uint_as_float(r3.y));
            fma_h(a0, h4, __uint_as_float(r4.y));
            fma_h(a1, h5, __uint_as_float(r5.y));
            fma_h(a2, h6, __uint_as_float(r6.y));
            fma_h(a3, h7, __uint_as_float(r7.y));
        }
        for (; e + 4 <= e1; e += 4) {
            uint2 r0 = eld[e], r1 = eld[e + 1], r2 = eld[e + 2], r3 = eld[e + 3];
            uint2 h0 = Hin[(size_t)r0.x * 4 + q];
            uint2 h1 = Hin[(size_t)r1.x * 4 + q];
            uint2 h2 = Hin[(size_t)r2.x * 4 + q];
            uint2 h3 = Hin[(size_t)r3.x * 4 + q];
            fma_h(a0, h0, __uint_as_float(r0.y));
            fma_h(a1, h1, __uint_as_float(r1.y));
            fma_h(a2, h2, __uint_as_float(r2.y));
            fma_h(a3, h3, __uint_as_float(r3.y));
        }
        for (; e < e1; ++e) {
            uint2 rr = eld[e];
            uint2 h = Hin[(size_t)rr.x * 4 + q];
            fma_h(a0, h, __uint_as_float(rr.y));
        }
        a0.x += a1.x + a2.x + a3.x;
        a0.y += a1.y + a2.y + a3.y;
        a0.z += a1.z + a2.z + a3.z;
        a0.w += a1.w + a2.w + a3.w;
    } else {
        a0.x = accf[lr * 17 + 4 * q];
        a0.y = accf[lr * 17 + 4 * q + 1];
        a0.z = accf[lr * 17 + 4 * q + 2];
        a0.w = accf[lr * 17 + 4 * q + 3];
    }
    float dg = deg[r];
    int ob = q * 16;
    const float4* bp = reinterpret_cast<const float4*>(&b2s[ob]);
    float4 c0 = bp[0], c1 = bp[1], c2 = bp[2], c3 = bp[3];
    c0.x *= dg; c0.y *= dg; c0.z *= dg; c0.w *= dg;
    c1.x *= dg; c1.y *= dg; c1.z *= dg; c1.w *= dg;
    c2.x *= dg; c2.y *= dg; c2.z *= dg; c2.w *= dg;
    c3.x *= dg; c3.y *= dg; c3.z *= dg; c3.w *= dg;
#pragma unroll
    for (int sq = 0; sq < 4; ++sq) {
        float tv[4];
        tv[0] = __shfl(a0.x, sq, 4);
        tv[1] = __shfl(a0.y, sq, 4);
        tv[2] = __shfl(a0.z, sq, 4);
        tv[3] = __shfl(a0.w, sq, 4);
#pragma unroll
        for (int j = 0; j < 4; ++j) {
            int h = 4 * sq + j;
            const float4* wp = reinterpret_cast<const float4*>(&w2[h * OUT_SIZE + ob]);
            float4 w0 = wp[0], w1 = wp[1], w2v = wp[2], w3 = wp[3];
            float th = tv[j];
            c0.x += th * w0.x; c0.y += th * w0.y; c0.z += th * w0.z; c0.w += th * w0.w;
            c1.x += th * w1.x; c1.y += th * w1.y; c1.z += th * w1.z; c1.w += th * w1.w;
            c2.x += th * w2v.x; c2.y += th * w2v.y; c2.z += th * w2v.z; c2.w += th * w2v.w;
            c3.x += th * w3.x; c3.y += th * w3.y; c3.z += th * w3.z; c3.w += th * w3.w;
        }
    }
    c0.x = fmaxf(c0.x, 0.f); c0.y = fmaxf(c0.y, 0.f); c0.z = fmaxf(c0.z, 0.f); c0.w = fmaxf(c0.w, 0.f);
    c1.x = fmaxf(c1.x, 0.f); c1.y = fmaxf(c1.y, 0.f); c1.z = fmaxf(c1.z, 0.f); c1.w = fmaxf(c1.w, 0.f);
    c2.x = fmaxf(c2.x, 0.f); c2.y = fmaxf(c2.y, 0.f); c2.z = fmaxf(c2.z, 0.f); c2.w = fmaxf(c2.w, 0.f);
    c3.x = fmaxf(c3.x, 0.f); c3.y = fmaxf(c3.y, 0.f); c3.z = fmaxf(c3.z, 0.f); c3.w = fmaxf(c3.w, 0.f);
    float4* op = reinterpret_cast<float4*>(out + (size_t)r * OUT_SIZE + ob);
    op[0] = c0; op[1] = c1; op[2] = c2; op[3] = c3;
}

// ---------------- atomic push spmm (fallback only) ----------------
__global__ __launch_bounds__(256) void spmm16_kernel(
    const int* __restrict__ row, const int* __restrict__ col,
    const float* __restrict__ val, const float* __restrict__ Hin,
    float* __restrict__ Sout, float* __restrict__ deg, long nedges, int relu_in) {
    long t = (long)blockIdx.x * 256 + threadIdx.x;
    long e = t >> 4;
    if (e >= nedges) return;
    int k = (int)(t & 15);
    int r = row[e];
    int c = col[e];
    float v = val[e];
    float x = Hin[(size_t)c * HIDDEN + k];
    if (relu_in) x = fmaxf(x, 0.0f);
    atomicAdd(&Sout[(size_t)r * HIDDEN + k], v * x);
    if (deg != nullptr && k == 0) atomicAdd(&deg[r], v);
}

// ---------------- dense2 (fallback only) ----------------
__global__ __launch_bounds__(256) void dense2_kernel(
    const float* __restrict__ T, const float* __restrict__ deg,
    const float* __restrict__ W2, const float* __restrict__ b2,
    float* __restrict__ out, int n) {
    __shared__ float w[OUT_SIZE * HIDDEN];
    for (int i = threadIdx.x; i < OUT_SIZE * HIDDEN; i += 256) {
        int o = i / HIDDEN;
        int h = i % HIDDEN;
        w[h * OUT_SIZE + o] = W2[i];
    }
    __syncthreads();
    int node = blockIdx.x * 4 + (threadIdx.x >> 6);
    int o = threadIdx.x & 63;
    if (node >= n) return;
    float acc = deg[node] * b2[o];
#pragma unroll
    for (int h = 0; h < HIDDEN; ++h)
        acc += T[(size_t)node * HIDDEN + h] * w[h * OUT_SIZE + o];
    out[(size_t)node * OUT_SIZE + o] = fmaxf(acc, 0.0f);
}

static inline char* align_up(char* p, size_t a) {
    return (char*)(((uintptr_t)p + a - 1) & ~(uintptr_t)(a - 1));
}

extern "C" void kernel_launch(void* const* d_in, const int* in_sizes, int n_in,
                              void* d_out, int out_size, void* d_ws, size_t ws_size,
                              hipStream_t stream) {
    const int*   index = (const int*)d_in[0];
    const float* value = (const float*)d_in[1];
    const float* X     = (const float*)d_in[4];
    const float* W1    = (const float*)d_in[5];
    const float* b1    = (const float*)d_in[6];
    const float* W2    = (const float*)d_in[7];
    const float* b2    = (const float*)d_in[8];
    float* out = (float*)d_out;

    long nedges = in_sizes[1];
    int  n      = in_sizes[4] / IN_SIZE;
    const int* row = index;
    const int* col = index + nedges;

    int nblk = (int)((nedges + EB - 1) / EB);
    int ncs  = (n + BROWS - 1) >> BSHIFT;

    size_t need = (size_t)nedges * 8 + (size_t)(NBUCK + 1) * nblk * 4 +
                  (size_t)ncs * CAP * 8 + (size_t)ncs * BROWS * 4 +
                  (size_t)ncs * 4 + (size_t)n * (32 + 32 + 4) + 1024;

    if (ws_size >= need && n <= (NBUCK << BSHIFT) && nblk <= NBLK_MAX) {
        char* p = (char*)d_ws;
        uint2* bin = (uint2*)p;       p += (size_t)nedges * 8;
        int* dirT  = (int*)p;         p += (size_t)(NBUCK + 1) * nblk * 4;
        uint2* epackS = (uint2*)p;    p += (size_t)ncs * CAP * 8;
        unsigned int* mcnt = (unsigned int*)p;  p += (size_t)ncs * BROWS * 4;
        int* minfo = (int*)p;         p += (size_t)ncs * 4;
        p = align_up(p, 64);
        __half2* H1h = (__half2*)p;   p += (size_t)n * 32;
        __half2* Ah  = (__half2*)p;   p += (size_t)n * 32;
        float* deg   = (float*)p;

        bin_kernel<<<nblk, BINBLK, 0, stream>>>(row, col, value, bin, dirT, nblk, nedges);
        dense1_half_kernel<<<(n + 63) / 64, 256, 0, stream>>>(X, W1, b1, H1h, n);
        csort_spmm1_kernel<<<ncs, 512, 0, stream>>>(
            bin, dirT, (const uint2*)H1h, Ah, deg, epackS, mcnt, minfo, n, nblk);
        spmm2_out_kernel<<<ncs, 512, 0, stream>>>(
            bin, dirT, epackS, mcnt, minfo, (const uint2*)Ah, W2, b2, deg,
            out, n, nblk);
    } else {
        float* ws = (float*)d_ws;
        float* H1  = ws;
        float* S1  = H1 + (size_t)n * HIDDEN;
        float* T   = S1 + (size_t)n * HIDDEN;
        float* deg = T + (size_t)n * HIDDEN;
        zero_int_kernel<<<2048, 256, 0, stream>>>((int*)S1, (long)n * (2 * HIDDEN + 1));
        dense1_kernel<<<(n + 15) / 16, 256, 0, stream>>>(X, W1, b1, H1, n);
        long thr1 = nedges * HIDDEN;
        spmm16_kernel<<<(int)((thr1 + 255) / 256), 256, 0, stream>>>(
            row, col, value, H1, S1, deg, nedges, 0);
        spmm16_kernel<<<(int)((thr1 + 255) / 256), 256, 0, stream>>>(
            row, col, value, S1, T, nullptr, nedges, 1);
        dense2_kernel<<<(n + 3) / 4, 256, 0, stream>>>(T, deg, W2, b2, out, n);
    }
}